// Round 9
// baseline (808.070 us; speedup 1.0000x reference)
//
#include <hip/hip_runtime.h>
#include <cstdint>

// Problem constants (fixed by the reference)
#define N_TRAIN 65536
#define N_TEST  4096
#define DIM     512
#define K_NN    5
#define NSEG    32
#define SEG     (N_TRAIN / NSEG)   // 2048 train cols per segment

// fp8 MFMA path tile config. D = Xtr_tile (M=128 train cols) x Xte_tile^T
// (N=128 test rows). 32x32x64 scaled MFMA (scales = 1.0): C/D layout
// col=lane&31 (test row), row=(reg&3)+8*(reg>>2)+4*(lane>>5) (train col).
//
// ROUND-8 STRUCTURE (test slab + train triple-buffer counted-vmcnt pipeline):
//   TEST slab (128 x 512 B = 64 KB) staged into LDS ONCE (R7-verified
//   swizzled layout), read-only afterwards.
//   TRAIN staged via global_load_lds (R4-verified swizzled addressing,
//   LDS multicast: each byte moves L2->LDS once) into a 3-deep ring
//   (3 x 16 KB), prefetched TWO steps ahead. Per step: one raw s_barrier +
//   s_waitcnt vmcnt(4) -- NEVER a vmcnt(0) drain in the main loop (T4).
#define GTM 128      // test rows per block (N dim)
#define GTN 128      // train cols per tile (M dim)
#define GBK 128      // K bytes (fp8 elems) consumed per step (2 MFMA K-halves)
#define NCAND (NSEG * K_NN)                 // 160 u32 candidates per test row
#define NRES  24                            // exactly-rescored candidates
#define NSTEP ((SEG / GTN) * (DIM / GBK))   // 16 col-tiles * 4 k-steps = 64
#define KMASK 0xFFFFF800u                   // 21-bit trunc dist | 11-bit col

typedef float f32x4  __attribute__((ext_vector_type(4)));
typedef float f32x16 __attribute__((ext_vector_type(16)));
typedef int   i32x8  __attribute__((ext_vector_type(8)));

#define GLDS16(g, l)                                                          \
    __builtin_amdgcn_global_load_lds(                                         \
        (__attribute__((address_space(1))) void*)(g),                         \
        (__attribute__((address_space(3))) void*)(l), 16, 0, 0)

// ---------------------------------------------------------------------------
// fp32 -> OCP e4m3fn (RNE, saturating). SW fallback bit-exact, header-free.
// ---------------------------------------------------------------------------
__device__ inline unsigned f2e4m3_sw(float x) {
    float ax = fabsf(x);
    unsigned sgn = (__float_as_uint(x) >> 31) << 7;
    if (ax != ax) return sgn | 0x7Fu;            // NaN
    if (ax >= 448.0f) return sgn | 0x7Eu;        // saturate to 448
    int ebits = (int)((__float_as_uint(ax) >> 23) & 0xFF);
    int e = ebits - 127;
    int shift = (e < -6 ? -6 : e) - 3;           // e4m3 quantum exponent
    float q = exp2f((float)shift);
    float r = rintf(ax / q) * q;                 // RNE onto the e4m3 grid
    if (r >= 448.0f) return sgn | 0x7Eu;
    if (r == 0.0f) return sgn;
    unsigned ru = __float_as_uint(r);
    int re = (int)((ru >> 23) & 0xFF) - 127;
    if (re < -6) {                               // e4m3 subnormal: k * 2^-9
        unsigned k = (unsigned)(r * 512.0f);
        return sgn | k;
    }
    unsigned rm = (ru >> 20) & 0x7u;
    return sgn | ((unsigned)(re + 7) << 3) | rm;
}

__device__ inline unsigned pk4_fp8(float x0, float x1, float x2, float x3) {
#if __has_builtin(__builtin_amdgcn_cvt_pk_fp8_f32)
    unsigned r = (unsigned)__builtin_amdgcn_cvt_pk_fp8_f32(x0, x1, 0, 0);
    r = (unsigned)__builtin_amdgcn_cvt_pk_fp8_f32(x2, x3, (int)r, 1);
    return r;
#else
    return f2e4m3_sw(x0) | (f2e4m3_sw(x1) << 8) |
           (f2e4m3_sw(x2) << 16) | (f2e4m3_sw(x3) << 24);
#endif
}

// ---------------------------------------------------------------------------
// Kernel 1: fused fp8(e4m3) convert + squared L2 row norms. One wave per row.
// ---------------------------------------------------------------------------
__global__ __launch_bounds__(256) void cvtnorm8_k(const float* __restrict__ in,
                                                  unsigned char* __restrict__ outb,
                                                  float* __restrict__ outn,
                                                  int nrows) {
    int row  = blockIdx.x * 4 + (threadIdx.x >> 6);
    int lane = threadIdx.x & 63;
    if (row >= nrows) return;
    const float4* p = (const float4*)(in + (size_t)row * DIM) + lane * 2;
    float4 a = p[0], b = p[1];
    float s = a.x*a.x + a.y*a.y + a.z*a.z + a.w*a.w
            + b.x*b.x + b.y*b.y + b.z*b.z + b.w*b.w;
    uint2 v;
    v.x = pk4_fp8(a.x, a.y, a.z, a.w);
    v.y = pk4_fp8(b.x, b.y, b.z, b.w);
    *((uint2*)(outb + (size_t)row * DIM) + lane) = v;
#pragma unroll
    for (int off = 32; off > 0; off >>= 1) s += __shfl_xor(s, off, 64);
    if (lane == 0) outn[row] = s;
}

// plain norms (fallback path)
__global__ __launch_bounds__(256) void norms_k(const float* __restrict__ X,
                                               float* __restrict__ out,
                                               int nrows) {
    int row  = blockIdx.x * 4 + (threadIdx.x >> 6);
    int lane = threadIdx.x & 63;
    if (row >= nrows) return;
    const float4* xp = (const float4*)(X + (size_t)row * DIM);
    float4 a = xp[lane];
    float4 b = xp[lane + 64];
    float s = a.x*a.x + a.y*a.y + a.z*a.z + a.w*a.w
            + b.x*b.x + b.y*b.y + b.z*b.z + b.w*b.w;
#pragma unroll
    for (int off = 32; off > 0; off >>= 1) s += __shfl_down(s, off, 64);
    if (lane == 0) out[row] = s;
}

// ---------------------------------------------------------------------------
// top-5 insertion (sorted ascending)
// ---------------------------------------------------------------------------
__device__ inline void ins5(unsigned long long key, unsigned long long* top) {
    if (key < top[4]) {
        unsigned long long k0 = top[0], k1 = top[1], k2 = top[2], k3 = top[3];
        top[0] = key < k0 ? key : k0;
        top[1] = key < k0 ? k0 : (key < k1 ? key : k1);
        top[2] = key < k1 ? k1 : (key < k2 ? key : k2);
        top[3] = key < k2 ? k2 : (key < k3 ? key : k3);
        top[4] = key < k3 ? k3 : key;
    }
}

__device__ inline void ins5u(unsigned key, unsigned* top) {
    if (key < top[4]) {
        unsigned k0 = top[0], k1 = top[1], k2 = top[2], k3 = top[3];
        top[0] = key < k0 ? key : k0;
        top[1] = key < k0 ? k0 : (key < k1 ? key : k1);
        top[2] = key < k1 ? k1 : (key < k2 ? key : k2);
        top[3] = key < k2 ? k2 : (key < k3 ? key : k3);
        top[4] = key < k3 ? k3 : key;
    }
}

// order-preserving float -> uint map (handles negatives)
__device__ inline unsigned fmono(float v) {
    unsigned u = __float_as_uint(v);
    return (u & 0x80000000u) ? ~u : (u | 0x80000000u);
}

#if __has_builtin(__builtin_amdgcn_mfma_scale_f32_32x32x64_f8f6f4)
// ===========================================================================
// Kernel 2 (primary): fp8 32x32x64 scaled-MFMA distance GEMM.
// Block 256 thr (4 waves, wr x wc = train-half x test-half, 64x64 each;
// per wave 2x2 tiles of 32x32). Tile 128 train x 128 test.
//
// LDS (112 KB total -> 1 block/CU):
//   As: test slab 128x512B, staged ONCE (R7-verified swizzle: logical
//       (row,c) at phys byte row*512 + (c ^ ((row&7)<<4)); 16B chunks
//       intact, logical k order preserved -> dot product exact).
//   Bs: train ring, 3 x (128x128B), R4-verified swizzle (row*128 +
//       (k ^ ((row&7)<<4))), filled by global_load_lds (L2->LDS multicast).
//
// SCHEDULE (T3/T4 counted vmcnt, depth-2 prefetch, one barrier/step):
//   step s: s_waitcnt vmcnt(4)  -- in-order vmcnt retirement => everything
//             older than the newest 4 loads (= stage(s+1)) has landed, i.e.
//             stage(s) is complete for THIS wave;
//           s_barrier            -- all waves' stage(s) landed; also proves
//             every wave finished its step-(s-1) ds_reads (those complete
//             before the step-(s-1) MFMAs, which precede this barrier), so
//             buf[(s+2)%3] == buf[(s-1)%3] is free for reuse;
//           stage(s+2) -> buf[(s+2)%3]   (4 global_load_lds / thread);
//           ds_read frags from buf[s%3] + As; 8 MFMA; epilogue at ct end.
//   Last step uses vmcnt(0) (drains the final stage). The main loop never
//   drains vmcnt to 0 otherwise -- loads stay in flight across barriers.
//
// C/D layout (measured, dtype-independent): col=lane&31 -> ONE test row per
// nt tile; row=(reg&3)+8*(reg>>2)+4*(lane>>5) -> 16 train cols per mt tile.
// Exactness: fp8 screening only must keep the true top-5 within the top-24
// rescore set (quant sigma ~1.7 << 5th-vs-24th gap ~19); final answer is
// exact fp32 (kernel 3). All layout/math components verified absmax=0 in
// rounds 4 and 7; only the sync schedule is new.
// ===========================================================================
__global__ __launch_bounds__(256, 1) void knn_mfma_k(
    const unsigned char* __restrict__ Xtr8,   // fp8 e4m3 [N_TRAIN][DIM]
    const unsigned char* __restrict__ Xte8,   // fp8 e4m3 [N_TEST][DIM]
    const float* __restrict__ x2,
    unsigned* __restrict__ cand)              // [N_TEST][NCAND] u32 keys
{
    __shared__ __align__(16) unsigned char As[GTM * DIM];     // test slab 64 KB
    __shared__ __align__(16) unsigned char Bs[3][GTN * GBK];  // train ring 48 KB

    const int t    = threadIdx.x;
    const int lane = t & 63;
    const int w    = t >> 6;
    const int wr   = w >> 1, wc = w & 1;   // wr: train half (M), wc: test half (N)
    const int l31  = lane & 31;            // row-within-32 for A/B frags; test row for C
    const int hi   = lane >> 5;            // K-half selector (frags) / +4 row off (C)
    const int r7   = lane & 7;             // swizzle row bits (row&7 == lane&7)
    const int row0 = blockIdx.x * GTM;
    const int seg0 = blockIdx.y * SEG;

    unsigned top5[2][K_NN];
#pragma unroll
    for (int nt = 0; nt < 2; ++nt)
#pragma unroll
        for (int p = 0; p < K_NN; ++p) top5[nt][p] = 0xFFFFFFFFu;

    // ---- one-time test staging (R7-verified): 4096 16B chunks, 16/thread --
    // phys chunk cs -> row = cs>>5, phys slot = cs&31; source slot keeps
    // bits 3..4 and XORs bits 0..2 with row&7 (inverse of the read XOR).
#pragma unroll
    for (int j = 0; j < 16; ++j) {
        const int cs = j * 256 + t;
        const int gr = cs >> 5;
        const int ss = (cs & 24) | ((cs ^ gr) & 7);
        GLDS16(Xte8 + (size_t)(row0 + gr) * DIM + (ss << 4),
               &As[(j * 256 + w * 64) * 16]);
    }

    // ---- train staging offsets (R4-verified): chunk cs = j*256+t ->
    // tile row cs>>3, swizzled 16B slot (cs ^ cs>>3)&7
    int off[4];
#pragma unroll
    for (int j = 0; j < 4; ++j) {
        const int cs = j * 256 + t;
        const int gr = cs >> 3;
        off[j] = gr * DIM + (((cs ^ gr) & 7) << 4);
    }

    // stage train step s (col-tile s>>2, k-chunk s&3) into ring buffer b
    auto stageT = [&](int s, int b) {
        const int k0 = (s & 3) * GBK;
        const unsigned char* bb = Xtr8 + (size_t)(seg0 + (s >> 2) * GTN) * DIM + k0;
#pragma unroll
        for (int j = 0; j < 4; ++j) {
            const int ldsb = (j * 256 + w * 64) * 16;   // wave-uniform dest base
            GLDS16(bb + off[j], &Bs[b][ldsb]);
        }
    };

    f32x16 acc[2][2];
    auto zero_acc = [&]() {
#pragma unroll
        for (int mt = 0; mt < 2; ++mt)
#pragma unroll
            for (int nt = 0; nt < 2; ++nt)
#pragma unroll
                for (int e = 0; e < 16; ++e) acc[mt][nt][e] = 0.f;
    };

    // per-ct register epilogue (identical to verified R7 epilogue)
    auto epilogue = [&](int ct) {
        const int col0 = seg0 + ct * GTN;
        f32x4 x2r[2][4];
#pragma unroll
        for (int mt = 0; mt < 2; ++mt)
#pragma unroll
            for (int g = 0; g < 4; ++g)
                x2r[mt][g] = *(const f32x4*)&x2[col0 + wr * 64 + mt * 32 + g * 8 + 4 * hi];
        const int cbase = ct * GTN + wr * 64;
#pragma unroll
        for (int nt = 0; nt < 2; ++nt) {
            float dv[2][16];
            float gm[2][4];
#pragma unroll
            for (int mt = 0; mt < 2; ++mt)
#pragma unroll
                for (int g = 0; g < 4; ++g) {
#pragma unroll
                    for (int i = 0; i < 4; ++i)
                        dv[mt][g * 4 + i] =
                            fmaf(-2.f, acc[mt][nt][g * 4 + i], x2r[mt][g][i]);
                    gm[mt][g] = fminf(fminf(dv[mt][g*4+0], dv[mt][g*4+1]),
                                      fminf(dv[mt][g*4+2], dv[mt][g*4+3]));
                }
            float dmin = fminf(
                fminf(fminf(gm[0][0], gm[0][1]), fminf(gm[0][2], gm[0][3])),
                fminf(fminf(gm[1][0], gm[1][1]), fminf(gm[1][2], gm[1][3])));
            if ((fmono(dmin) & KMASK) <= top5[nt][4]) {   // rare path
#pragma unroll
                for (int mt = 0; mt < 2; ++mt)
#pragma unroll
                    for (int g = 0; g < 4; ++g) {
                        if ((fmono(gm[mt][g]) & KMASK) <= top5[nt][4]) {
#pragma unroll
                            for (int i = 0; i < 4; ++i) {
                                unsigned key = (fmono(dv[mt][g * 4 + i]) & KMASK)
                                    | (unsigned)(cbase + mt * 32 + g * 8 + 4 * hi + i);
                                ins5u(key, top5[nt]);
                            }
                        }
                    }
            }
        }
    };

    // prologue: prime ring with steps 0 and 1; full drain once (also covers
    // the test slab staging).
    stageT(0, 0);
    stageT(1, 1);
    __syncthreads();

    zero_acc();

#pragma unroll 1
    for (int s = 0; s < NSTEP; ++s) {
        // counted wait: all but the newest 4 loads (stage(s+1)) have landed
        // -> stage(s) complete for this wave. Last step drains everything.
        if (s < NSTEP - 1) {
            asm volatile("s_waitcnt vmcnt(4)" ::: "memory");
        } else {
            asm volatile("s_waitcnt vmcnt(0)" ::: "memory");
        }
        __builtin_amdgcn_s_barrier();   // all waves' stage(s) landed;
                                        // buf[(s+2)%3] free for reuse
        if (s + 2 < NSTEP) stageT(s + 2, (s + 2) % 3);

        const unsigned char* Bb = Bs[s % 3];
        const int kkb = (s & 3) * GBK;
#pragma unroll
        for (int ks = 0; ks < 2; ++ks) {        // two K=64 halves
            const int xq = (ks * 64 + hi * 32) ^ (r7 << 4);
            i32x8 trf[2], tef[2];
#pragma unroll
            for (int mt = 0; mt < 2; ++mt) {    // A = train rows (M), from ring
                const unsigned char* p = &Bb[(wr * 64 + mt * 32 + l31) * GBK];
                int4 lo = *(const int4*)&p[xq];
                int4 hx = *(const int4*)&p[xq ^ 16];
                trf[mt] = (i32x8){lo.x, lo.y, lo.z, lo.w, hx.x, hx.y, hx.z, hx.w};
            }
#pragma unroll
            for (int nt = 0; nt < 2; ++nt) {    // B = test rows (N), from slab
                const unsigned char* p = &As[(wc * 64 + nt * 32 + l31) * DIM + kkb];
                int4 lo = *(const int4*)&p[xq];
                int4 hx = *(const int4*)&p[xq ^ 16];
                tef[nt] = (i32x8){lo.x, lo.y, lo.z, lo.w, hx.x, hx.y, hx.z, hx.w};
            }
#pragma unroll
            for (int mt = 0; mt < 2; ++mt)
#pragma unroll
                for (int nt = 0; nt < 2; ++nt)
                    acc[mt][nt] = __builtin_amdgcn_mfma_scale_f32_32x32x64_f8f6f4(
                        trf[mt], tef[nt], acc[mt][nt],
                        0 /*A=e4m3*/, 0 /*B=e4m3*/,
                        0, 0x7F7F7F7F, 0, 0x7F7F7F7F /* scales = 2^0 */);
        }

        if ((s & 3) == 3) {             // ct boundary (uniform branch)
            epilogue(s >> 2);
            zero_acc();
        }
    }

    // final merge through (now dead) train ring: 256 thr x 10 keys = 10 KB
    __syncthreads();
    unsigned* MB = (unsigned*)&Bs[0][0];
#pragma unroll
    for (int nt = 0; nt < 2; ++nt)
#pragma unroll
        for (int p = 0; p < K_NN; ++p) MB[t * 10 + nt * K_NN + p] = top5[nt][p];
    __syncthreads();

    // one thread per test row, merge 4 sub-lists (wr x hi) of 5
    if (t < GTM) {
        const int r   = t;
        const int mwc = r >> 6, mnt = (r >> 5) & 1, mn5 = r & 31;
        unsigned tp[K_NN];
#pragma unroll
        for (int p = 0; p < K_NN; ++p) tp[p] = 0xFFFFFFFFu;
#pragma unroll
        for (int w2 = 0; w2 < 2; ++w2)          // wr
#pragma unroll
            for (int h2 = 0; h2 < 2; ++h2) {    // hi
                const int tid = (w2 * 2 + mwc) * 64 + h2 * 32 + mn5;
                const unsigned* src = &MB[tid * 10 + mnt * K_NN];
#pragma unroll
                for (int p = 0; p < K_NN; ++p) ins5u(src[p], tp);
            }
        unsigned* cr = cand + (size_t)(row0 + r) * NCAND + blockIdx.y * K_NN;
#pragma unroll
        for (int p = 0; p < K_NN; ++p) cr[p] = tp[p];
    }
}

#else
// ===========================================================================
// Kernel 2 (fallback toolchain path): round-3 16x16 version, known-compiling.
// ===========================================================================
#if __has_builtin(__builtin_amdgcn_mfma_scale_f32_16x16x128_f8f6f4)
__device__ inline f32x4 mfma_k128(i32x8 a, i32x8 b, f32x4 c) {
    return __builtin_amdgcn_mfma_scale_f32_16x16x128_f8f6f4(
        a, b, c, 0, 0, 0, 0x7F7F7F7F, 0, 0x7F7F7F7F);
}
#else
__device__ inline long long mk64(int lo, int hi) {
    return (long long)(((unsigned long long)(unsigned)hi << 32) | (unsigned)lo);
}
__device__ inline f32x4 mfma_k128(i32x8 a, i32x8 b, f32x4 c) {
    c = __builtin_amdgcn_mfma_f32_16x16x32_fp8_fp8(mk64(a[0],a[1]), mk64(b[0],b[1]), c, 0,0,0);
    c = __builtin_amdgcn_mfma_f32_16x16x32_fp8_fp8(mk64(a[2],a[3]), mk64(b[2],b[3]), c, 0,0,0);
    c = __builtin_amdgcn_mfma_f32_16x16x32_fp8_fp8(mk64(a[4],a[5]), mk64(b[4],b[5]), c, 0,0,0);
    c = __builtin_amdgcn_mfma_f32_16x16x32_fp8_fp8(mk64(a[6],a[7]), mk64(b[6],b[7]), c, 0,0,0);
    return c;
}
#endif

__global__ __launch_bounds__(256, 2) void knn_mfma_k(
    const unsigned char* __restrict__ Xtr8,
    const unsigned char* __restrict__ Xte8,
    const float* __restrict__ x2,
    unsigned* __restrict__ cand)
{
    __shared__ __align__(16) unsigned char As[2][GTM * GBK];
    __shared__ __align__(16) unsigned char Bs[2][GTN * GBK];

    const int t     = threadIdx.x;
    const int lane  = t & 63;
    const int w     = t >> 6;
    const int wr    = w >> 1, wc = w & 1;
    const int col_l = lane & 15, quad = lane >> 4;
    const int row0  = blockIdx.x * GTM;
    const int seg0  = blockIdx.y * SEG;

    unsigned top5[4][K_NN];
#pragma unroll
    for (int nt = 0; nt < 4; ++nt)
#pragma unroll
        for (int p = 0; p < K_NN; ++p) top5[nt][p] = 0xFFFFFFFFu;

    int off[4];
#pragma unroll
    for (int j = 0; j < 4; ++j) {
        const int cs = j * 256 + t;
        const int gr = cs >> 3;
        off[j] = gr * DIM + (((cs ^ gr) & 7) << 4);
    }

    auto stage = [&](int s, int b) {
        const int k0 = (s & 3) * GBK;
        const unsigned char* ab = Xte8 + (size_t)row0 * DIM + k0;
        const unsigned char* bb = Xtr8 + (size_t)(seg0 + (s >> 2) * GTN) * DIM + k0;
#pragma unroll
        for (int j = 0; j < 4; ++j) {
            const int ldsb = (j * 256 + w * 64) * 16;
            GLDS16(ab + off[j], &As[b][ldsb]);
            GLDS16(bb + off[j], &Bs[b][ldsb]);
        }
    };

    stage(0, 0);
    __syncthreads();

    const int xq = (quad * 32) ^ ((lane & 7) << 4);

#pragma unroll 1
    for (int ct = 0; ct < SEG / GTN; ++ct) {
        const int col0 = seg0 + ct * GTN;
        f32x4 acc[4][4];
#pragma unroll
        for (int mt = 0; mt < 4; ++mt)
#pragma unroll
            for (int nt = 0; nt < 4; ++nt)
                acc[mt][nt] = (f32x4){0.f, 0.f, 0.f, 0.f};

        f32x4 x2r[4];
#pragma unroll
        for (int mt = 0; mt < 4; ++mt)
            x2r[mt] = *(const f32x4*)&x2[col0 + wr * 64 + mt * 16 + quad * 4];

#pragma unroll 1
        for (int kk = 0; kk < DIM / GBK; ++kk) {
            const int s = ct * (DIM / GBK) + kk;
            if (s + 1 < NSTEP) stage(s + 1, (kk + 1) & 1);

            const unsigned char* Ab = As[kk & 1];
            const unsigned char* Bb = Bs[kk & 1];
            i32x8 trf[4], tef[4];
#pragma unroll
            for (int mt = 0; mt < 4; ++mt) {
                const unsigned char* p = &Bb[(wr * 64 + mt * 16 + col_l) * GBK];
                int4 lo = *(const int4*)&p[xq];
                int4 hx = *(const int4*)&p[xq ^ 16];
                trf[mt] = (i32x8){lo.x, lo.y, lo.z, lo.w, hx.x, hx.y, hx.z, hx.w};
            }
#pragma unroll
            for (int nt = 0; nt < 4; ++nt) {
                const unsigned char* p = &Ab[(wc * 64 + nt * 16 + col_l) * GBK];
                int4 lo = *(const int4*)&p[xq];
                int4 hx = *(const int4*)&p[xq ^ 16];
                tef[nt] = (i32x8){lo.x, lo.y, lo.z, lo.w, hx.x, hx.y, hx.z, hx.w};
            }
#pragma unroll
            for (int mt = 0; mt < 4; ++mt)
#pragma unroll
                for (int nt = 0; nt < 4; ++nt)
                    acc[mt][nt] = mfma_k128(trf[mt], tef[nt], acc[mt][nt]);

            __syncthreads();
        }

        const int cb = ct * GTN + wr * 64 + quad * 4;
#pragma unroll
        for (int nt = 0; nt < 4; ++nt) {
            float dv[16];
            float dmin = __builtin_inff();
#pragma unroll
            for (int mt = 0; mt < 4; ++mt) {
                f32x4 a = acc[mt][nt];
                dv[mt * 4 + 0] = fmaf(-2.f, a.x, x2r[mt].x);
                dv[mt * 4 + 1] = fmaf(-2.f, a.y, x2r[mt].y);
                dv[mt * 4 + 2] = fmaf(-2.f, a.z, x2r[mt].z);
                dv[mt * 4 + 3] = fmaf(-2.f, a.w, x2r[mt].w);
                float g = fminf(fminf(dv[mt*4+0], dv[mt*4+1]),
                                fminf(dv[mt*4+2], dv[mt*4+3]));
                dmin = fminf(dmin, g);
            }
            if ((fmono(dmin) & KMASK) <= top5[nt][4]) {
#pragma unroll
                for (int mt = 0; mt < 4; ++mt) {
                    float g = fminf(fminf(dv[mt*4+0], dv[mt*4+1]),
                                    fminf(dv[mt*4+2], dv[mt*4+3]));
                    if ((fmono(g) & KMASK) <= top5[nt][4]) {
#pragma unroll
                        for (int i = 0; i < 4; ++i) {
                            unsigned key = (fmono(dv[mt * 4 + i]) & KMASK)
                                         | (unsigned)(cb + mt * 16 + i);
                            ins5u(key, top5[nt]);
                        }
                    }
                }
            }
        }
    }

    __syncthreads();
    unsigned* MB = (unsigned*)&As[0][0];
#pragma unroll
    for (int nt = 0; nt < 4; ++nt)
#pragma unroll
        for (int p = 0; p < K_NN; ++p) MB[t * 20 + nt * K_NN + p] = top5[nt][p];
    __syncthreads();

    if (t < GTM) {
        const int r   = t;
        const int mwc = r >> 6, mnt = (r >> 4) & 3, mcl = r & 15;
        unsigned tp[K_NN];
#pragma unroll
        for (int p = 0; p < K_NN; ++p) tp[p] = 0xFFFFFFFFu;
#pragma unroll
        for (int w2 = 0; w2 < 2; ++w2)
#pragma unroll
            for (int q = 0; q < 4; ++q) {
                const int tid = (w2 * 2 + mwc) * 64 + q * 16 + mcl;
                const unsigned* src = &MB[tid * 20 + mnt * K_NN];
#pragma unroll
                for (int p = 0; p < K_NN; ++p) ins5u(src[p], tp);
            }
        unsigned* cr = cand + (size_t)(row0 + r) * NCAND + blockIdx.y * K_NN;
#pragma unroll
        for (int p = 0; p < K_NN; ++p) cr[p] = tp[p];
    }
}
#endif

// ---------------------------------------------------------------------------
// Kernel 3: fused approx-merge (160 -> top-24) + exact fp32 rescore + vote.
// One wave per test row. cand entries are u32: trunc-dist(21) | col-local(11);
// global col = (entry_index/5)*SEG + col-local.
// ---------------------------------------------------------------------------
__global__ __launch_bounds__(256) void rescore_vote_k(
    const float* __restrict__ Xtr, const float* __restrict__ Xte,
    const float* __restrict__ x2,  const float* __restrict__ t2,
    const unsigned* __restrict__ cand,
    const int* __restrict__ y, int* __restrict__ out)
{
    int row  = blockIdx.x * 4 + (threadIdx.x >> 6);
    int lane = threadIdx.x & 63;
    const unsigned* cr = cand + (size_t)row * NCAND;

    auto expand = [](unsigned k, int e) -> unsigned long long {
        unsigned gcol = (unsigned)(e / K_NN) * SEG + (k & 0x7FFu);
        return ((unsigned long long)k << 32) | gcol;
    };
    unsigned long long c0 = expand(cr[lane], lane);
    unsigned long long c1 = expand(cr[64 + lane], 64 + lane);
    unsigned long long c2 = (lane < NCAND - 128)
                          ? expand(cr[128 + lane], 128 + lane) : ~0ull;

    // iteratively extract the NRES smallest approx keys (all lanes get cols)
    unsigned cols[NRES];
#pragma unroll 1
    for (int i = 0; i < NRES; ++i) {
        unsigned long long m = c0 < c1 ? c0 : c1;
        m = c2 < m ? c2 : m;
#pragma unroll
        for (int off = 32; off > 0; off >>= 1) {
            unsigned long long o = __shfl_xor(m, off, 64);
            m = o < m ? o : m;
        }
        cols[i] = (unsigned)(m & 0xffffffffu);
        if (c0 == m) c0 = ~0ull;
        if (c1 == m) c1 = ~0ull;
        if (c2 == m) c2 = ~0ull;
    }

    // exact fp32 rescore of the NRES candidates
    const float4* te = (const float4*)(Xte + (size_t)row * DIM);
    float4 e0 = te[lane * 2], e1 = te[lane * 2 + 1];
    float t2r = t2[row];
    float d2s[NRES];
#pragma unroll 4
    for (int i = 0; i < NRES; ++i) {
        const float4* tr = (const float4*)(Xtr + (size_t)cols[i] * DIM);
        float4 p = tr[lane * 2], q = tr[lane * 2 + 1];
        float s = e0.x * p.x;
        s = fmaf(e0.y, p.y, s); s = fmaf(e0.z, p.z, s); s = fmaf(e0.w, p.w, s);
        s = fmaf(e1.x, q.x, s); s = fmaf(e1.y, q.y, s);
        s = fmaf(e1.z, q.z, s); s = fmaf(e1.w, q.w, s);
#pragma unroll
        for (int off = 32; off > 0; off >>= 1) s += __shfl_xor(s, off, 64);
        d2s[i] = fmaxf(t2r + x2[cols[i]] - 2.0f * s, 0.0f);
    }

    // exact top-5 (all lanes redundantly) + mode vote on lane 0
    unsigned long long top[K_NN];
#pragma unroll
    for (int p = 0; p < K_NN; ++p) top[p] = ~0ull;
#pragma unroll
    for (int i = 0; i < NRES; ++i)
        ins5(((unsigned long long)__float_as_uint(d2s[i]) << 32) | cols[i], top);

    if (lane == 0) {
        int labs[K_NN];
#pragma unroll
        for (int p = 0; p < K_NN; ++p) labs[p] = y[(unsigned)(top[p] & 0xffffffffu)];
        int bestLab = 0x7fffffff, bestCnt = 0;
#pragma unroll
        for (int p = 0; p < K_NN; ++p) {
            int cnt = 0;
#pragma unroll
            for (int q = 0; q < K_NN; ++q) cnt += (labs[q] == labs[p]) ? 1 : 0;
            if (cnt > bestCnt || (cnt == bestCnt && labs[p] < bestLab)) {
                bestCnt = cnt; bestLab = labs[p];
            }
        }
        out[row] = bestLab;
    }
}

// ===========================================================================
// Fallback fp32 path (round-1, verified) in case ws_size is too small.
// ===========================================================================
#define FTM 64
#define FTN 128
#define FBK 16
#define FSEG (N_TRAIN / 8)

__global__ __launch_bounds__(256) void knn_tile_k(
    const float* __restrict__ Xtr, const float* __restrict__ Xte,
    const float* __restrict__ x2,  const float* __restrict__ t2,
    unsigned long long* __restrict__ cand)
{
    __shared__ float As[FBK][FTM];
    __shared__ float Bs[FBK][FTN];
    __shared__ unsigned long long MB[FTM][16 * K_NN];

    const int t   = threadIdx.x;
    const int ty  = t >> 4;
    const int tx  = t & 15;
    const int row0 = blockIdx.x * FTM;
    const int seg0 = blockIdx.y * FSEG;

    float t2r[4];
#pragma unroll
    for (int j = 0; j < 4; ++j) t2r[j] = t2[row0 + ty * 4 + j];

    unsigned long long top[4][K_NN];
#pragma unroll
    for (int j = 0; j < 4; ++j)
#pragma unroll
        for (int p = 0; p < K_NN; ++p) top[j][p] = ~0ull;

    const int srow = t >> 2;
    const int skq  = (t & 3) * 4;

    for (int ct = 0; ct < FSEG / FTN; ++ct) {
        const int col0 = seg0 + ct * FTN;
        float acc[4][8] = {};

        for (int k0 = 0; k0 < DIM; k0 += FBK) {
            float4 av  = *(const float4*)(Xte + (size_t)(row0 + srow) * DIM + k0 + skq);
            float4 bv0 = *(const float4*)(Xtr + (size_t)(col0 + srow) * DIM + k0 + skq);
            float4 bv1 = *(const float4*)(Xtr + (size_t)(col0 + 64 + srow) * DIM + k0 + skq);
            __syncthreads();
            As[skq + 0][srow] = av.x;  As[skq + 1][srow] = av.y;
            As[skq + 2][srow] = av.z;  As[skq + 3][srow] = av.w;
            Bs[skq + 0][srow] = bv0.x; Bs[skq + 1][srow] = bv0.y;
            Bs[skq + 2][srow] = bv0.z; Bs[skq + 3][srow] = bv0.w;
            Bs[skq + 0][srow + 64] = bv1.x; Bs[skq + 1][srow + 64] = bv1.y;
            Bs[skq + 2][srow + 64] = bv1.z; Bs[skq + 3][srow + 64] = bv1.w;
            __syncthreads();

#pragma unroll
            for (int k = 0; k < FBK; ++k) {
                float4 a  = *(const float4*)&As[k][ty * 4];
                float4 b0 = *(const float4*)&Bs[k][tx * 8];
                float4 b1 = *(const float4*)&Bs[k][tx * 8 + 4];
                float a4[4] = {a.x, a.y, a.z, a.w};
                float b8[8] = {b0.x, b0.y, b0.z, b0.w, b1.x, b1.y, b1.z, b1.w};
#pragma unroll
                for (int j = 0; j < 4; ++j)
#pragma unroll
                    for (int l = 0; l < 8; ++l)
                        acc[j][l] = fmaf(a4[j], b8[l], acc[j][l]);
            }
        }

#pragma unroll
        for (int j = 0; j < 4; ++j) {
#pragma unroll
            for (int l = 0; l < 8; ++l) {
                int col = col0 + tx * 8 + l;
                float d2 = fmaxf(t2r[j] + x2[col] - 2.0f * acc[j][l], 0.0f);
                unsigned long long key =
                    ((unsigned long long)__float_as_uint(d2) << 32) | (unsigned)col;
                ins5(key, top[j]);
            }
        }
    }

#pragma unroll
    for (int j = 0; j < 4; ++j)
#pragma unroll
        for (int p = 0; p < K_NN; ++p)
            MB[ty * 4 + j][tx * K_NN + p] = top[j][p];
    __syncthreads();

    if (t < FTM) {
        unsigned long long last = 0;
        for (int p = 0; p < K_NN; ++p) {
            unsigned long long best = ~0ull;
            for (int q = 0; q < 16 * K_NN; ++q) {
                unsigned long long v = MB[t][q];
                if (v > last && v < best) best = v;
            }
            cand[(size_t)(row0 + t) * 40 + blockIdx.y * K_NN + p] = best;
            last = best;
        }
    }
}

__global__ __launch_bounds__(256) void knn_final_k(
    const unsigned long long* __restrict__ cand,
    const int* __restrict__ y, int* __restrict__ out)
{
    int r = blockIdx.x * 256 + threadIdx.x;
    if (r >= N_TEST) return;
    const unsigned long long* c = cand + (size_t)r * 40;

    unsigned long long top[K_NN];
#pragma unroll
    for (int p = 0; p < K_NN; ++p) top[p] = ~0ull;
#pragma unroll
    for (int i = 0; i < 40; ++i) ins5(c[i], top);

    int labs[K_NN];
#pragma unroll
    for (int p = 0; p < K_NN; ++p) labs[p] = y[(unsigned)(top[p] & 0xffffffffu)];

    int bestLab = 0x7fffffff, bestCnt = 0;
#pragma unroll
    for (int p = 0; p < K_NN; ++p) {
        int cnt = 0;
#pragma unroll
        for (int q = 0; q < K_NN; ++q) cnt += (labs[q] == labs[p]) ? 1 : 0;
        if (cnt > bestCnt || (cnt == bestCnt && labs[p] < bestLab)) {
            bestCnt = cnt; bestLab = labs[p];
        }
    }
    out[r] = bestLab;
}

// ---------------------------------------------------------------------------
// Workspace layout (fp8 path), bytes (NEED unchanged — known-good size):
//   [0,        262144)   x2     : 65536 f32
//   [262144,   278528)   t2     : 4096 f32
//   [278528,  2899968)   cand   : 4096 * 160 u32
//   [3145728, 5242880)   Xte_f8 : 4096*512  e4m3 (2 MB)
//   [7340032, 40894464)  Xtr_f8 : 65536*512 e4m3 (32 MB)
// ---------------------------------------------------------------------------
extern "C" void kernel_launch(void* const* d_in, const int* in_sizes, int n_in,
                              void* d_out, int out_size, void* d_ws, size_t ws_size,
                              hipStream_t stream) {
    const float* Xtr = (const float*)d_in[0];
    const float* Xte = (const float*)d_in[1];
    const int*   y   = (const int*)d_in[2];
    int* out = (int*)d_out;

    char* ws = (char*)d_ws;
    float* x2 = (float*)ws;
    float* t2 = (float*)(ws + 262144);

    const size_t NEED = 74448896;

    if (ws_size >= NEED) {
        unsigned* cand = (unsigned*)(ws + 278528);
        unsigned char* Xte8 = (unsigned char*)(ws + 3145728);
        unsigned char* Xtr8 = (unsigned char*)(ws + 7340032);

        cvtnorm8_k<<<N_TRAIN / 4, 256, 0, stream>>>(Xtr, Xtr8, x2, N_TRAIN);
        cvtnorm8_k<<<N_TEST / 4, 256, 0, stream>>>(Xte, Xte8, t2, N_TEST);

        knn_mfma_k<<<dim3(N_TEST / GTM, NSEG), 256, 0, stream>>>(Xtr8, Xte8, x2, cand);
        rescore_vote_k<<<N_TEST / 4, 256, 0, stream>>>(Xtr, Xte, x2, t2, cand, y, out);
    } else {
        // fp32 fallback (round-1 verified path); cand here is [N_TEST][40] u64
        unsigned long long* cand = (unsigned long long*)(ws + 278528);
        norms_k<<<N_TRAIN / 4, 256, 0, stream>>>(Xtr, x2, N_TRAIN);
        norms_k<<<N_TEST / 4, 256, 0, stream>>>(Xte, t2, N_TEST);
        knn_tile_k<<<dim3(N_TEST / FTM, 8), 256, 0, stream>>>(Xtr, Xte, x2, t2, cand);
        knn_final_k<<<N_TEST / 256, 256, 0, stream>>>(cand, y, out);
    }
}

// Round 10
// 552.319 us; speedup vs baseline: 1.4630x; 1.4630x over previous
//
#include <hip/hip_runtime.h>
#include <cstdint>

// Problem constants (fixed by the reference)
#define N_TRAIN 65536
#define N_TEST  4096
#define DIM     512
#define K_NN    5
#define NSEG    32
#define SEG     (N_TRAIN / NSEG)   // 2048 train cols per segment

// fp8 32x32x64 scaled-MFMA path. C/D layout (measured, dtype-independent):
// col=lane&31 (test row), row=(reg&3)+8*(reg>>2)+4*(lane>>5) (train col).
//
// ROUND-10 STRUCTURE (R4's verified 2-phase, scaled to m201 footprint):
//   512-thr blocks (8 waves = 2/SIMD -- the occupancy R4 had and R9 lost),
//   tile 128 test x 256 train, LDS 128 KB:
//     As[4][128x128B] = the test tile's ENTIRE K=512, staged ONCE in the
//       prologue (R4 re-staged the same data 16x);
//     Bs[2][256x128B] = train double-buffer, staged per step via
//       global_load_lds exactly like R4 (L2->LDS multicast).
//   Per-wave inner code identical to R4 (2x2 tiles of 32x32, acc 64).
//
// CONFLICT-FREE swizzle (upgrade of the verified involution): f3(row) =
//   (row&7) ^ ((row>>3)&3). Old row&7-only left rows ===mod 8 colliding
//   4-way (measured 1.69e7 conflict-cycles ~ 9%). With f3, the 32 lanes of
//   a frag read map to 32 distinct banks (enumerated). Same both-sides
//   rule: gload_lds writes linearly, SOURCE address carries the inverse;
//   XOR touches byte-bits 4..6 only -> 16B chunks intact, per-row logical
//   k order preserved -> dot product exact (same argument verified R4/R7).
#define BTM 128      // test rows per block (N dim)
#define BTN 256      // train cols per tile (M dim)
#define GBK 128      // K bytes (fp8 elems) consumed per step (2 MFMA K-halves)
#define NCAND (NSEG * K_NN)                 // 160 u32 candidates per test row
#define NRES  24                            // exactly-rescored candidates
#define NSTEP ((SEG / BTN) * (DIM / GBK))   // 8 col-tiles * 4 k-steps = 32
#define KMASK 0xFFFFF800u                   // 21-bit trunc dist | 11-bit col

typedef float f32x4  __attribute__((ext_vector_type(4)));
typedef float f32x16 __attribute__((ext_vector_type(16)));
typedef int   i32x8  __attribute__((ext_vector_type(8)));

#define GLDS16(g, l)                                                          \
    __builtin_amdgcn_global_load_lds(                                         \
        (__attribute__((address_space(1))) void*)(g),                         \
        (__attribute__((address_space(3))) void*)(l), 16, 0, 0)

// ---------------------------------------------------------------------------
// fp32 -> OCP e4m3fn (RNE, saturating). SW fallback bit-exact, header-free.
// ---------------------------------------------------------------------------
__device__ inline unsigned f2e4m3_sw(float x) {
    float ax = fabsf(x);
    unsigned sgn = (__float_as_uint(x) >> 31) << 7;
    if (ax != ax) return sgn | 0x7Fu;            // NaN
    if (ax >= 448.0f) return sgn | 0x7Eu;        // saturate to 448
    int ebits = (int)((__float_as_uint(ax) >> 23) & 0xFF);
    int e = ebits - 127;
    int shift = (e < -6 ? -6 : e) - 3;           // e4m3 quantum exponent
    float q = exp2f((float)shift);
    float r = rintf(ax / q) * q;                 // RNE onto the e4m3 grid
    if (r >= 448.0f) return sgn | 0x7Eu;
    if (r == 0.0f) return sgn;
    unsigned ru = __float_as_uint(r);
    int re = (int)((ru >> 23) & 0xFF) - 127;
    if (re < -6) {                               // e4m3 subnormal: k * 2^-9
        unsigned k = (unsigned)(r * 512.0f);
        return sgn | k;
    }
    unsigned rm = (ru >> 20) & 0x7u;
    return sgn | ((unsigned)(re + 7) << 3) | rm;
}

__device__ inline unsigned pk4_fp8(float x0, float x1, float x2, float x3) {
#if __has_builtin(__builtin_amdgcn_cvt_pk_fp8_f32)
    unsigned r = (unsigned)__builtin_amdgcn_cvt_pk_fp8_f32(x0, x1, 0, 0);
    r = (unsigned)__builtin_amdgcn_cvt_pk_fp8_f32(x2, x3, (int)r, 1);
    return r;
#else
    return f2e4m3_sw(x0) | (f2e4m3_sw(x1) << 8) |
           (f2e4m3_sw(x2) << 16) | (f2e4m3_sw(x3) << 24);
#endif
}

// ---------------------------------------------------------------------------
// Kernel 1: fused fp8(e4m3) convert + squared L2 row norms. One wave per row.
// ---------------------------------------------------------------------------
__global__ __launch_bounds__(256) void cvtnorm8_k(const float* __restrict__ in,
                                                  unsigned char* __restrict__ outb,
                                                  float* __restrict__ outn,
                                                  int nrows) {
    int row  = blockIdx.x * 4 + (threadIdx.x >> 6);
    int lane = threadIdx.x & 63;
    if (row >= nrows) return;
    const float4* p = (const float4*)(in + (size_t)row * DIM) + lane * 2;
    float4 a = p[0], b = p[1];
    float s = a.x*a.x + a.y*a.y + a.z*a.z + a.w*a.w
            + b.x*b.x + b.y*b.y + b.z*b.z + b.w*b.w;
    uint2 v;
    v.x = pk4_fp8(a.x, a.y, a.z, a.w);
    v.y = pk4_fp8(b.x, b.y, b.z, b.w);
    *((uint2*)(outb + (size_t)row * DIM) + lane) = v;
#pragma unroll
    for (int off = 32; off > 0; off >>= 1) s += __shfl_xor(s, off, 64);
    if (lane == 0) outn[row] = s;
}

// plain norms (fallback path)
__global__ __launch_bounds__(256) void norms_k(const float* __restrict__ X,
                                               float* __restrict__ out,
                                               int nrows) {
    int row  = blockIdx.x * 4 + (threadIdx.x >> 6);
    int lane = threadIdx.x & 63;
    if (row >= nrows) return;
    const float4* xp = (const float4*)(X + (size_t)row * DIM);
    float4 a = xp[lane];
    float4 b = xp[lane + 64];
    float s = a.x*a.x + a.y*a.y + a.z*a.z + a.w*a.w
            + b.x*b.x + b.y*b.y + b.z*b.z + b.w*b.w;
#pragma unroll
    for (int off = 32; off > 0; off >>= 1) s += __shfl_down(s, off, 64);
    if (lane == 0) out[row] = s;
}

// ---------------------------------------------------------------------------
// top-5 insertion (sorted ascending)
// ---------------------------------------------------------------------------
__device__ inline void ins5(unsigned long long key, unsigned long long* top) {
    if (key < top[4]) {
        unsigned long long k0 = top[0], k1 = top[1], k2 = top[2], k3 = top[3];
        top[0] = key < k0 ? key : k0;
        top[1] = key < k0 ? k0 : (key < k1 ? key : k1);
        top[2] = key < k1 ? k1 : (key < k2 ? key : k2);
        top[3] = key < k2 ? k2 : (key < k3 ? key : k3);
        top[4] = key < k3 ? k3 : key;
    }
}

__device__ inline void ins5u(unsigned key, unsigned* top) {
    if (key < top[4]) {
        unsigned k0 = top[0], k1 = top[1], k2 = top[2], k3 = top[3];
        top[0] = key < k0 ? key : k0;
        top[1] = key < k0 ? k0 : (key < k1 ? key : k1);
        top[2] = key < k1 ? k1 : (key < k2 ? key : k2);
        top[3] = key < k2 ? k2 : (key < k3 ? key : k3);
        top[4] = key < k3 ? k3 : key;
    }
}

// order-preserving float -> uint map (handles negatives)
__device__ inline unsigned fmono(float v) {
    unsigned u = __float_as_uint(v);
    return (u & 0x80000000u) ? ~u : (u | 0x80000000u);
}

// ===========================================================================
// Kernel 2: fp8 32x32x64 scaled-MFMA distance GEMM (R10 structure).
// 512 thr = 8 waves: wr = w>>1 in 0..3 (64-train-row quarter), wc = w&1
// (64-test-row half); per wave 2x2 tiles of 32x32 (identical to R4).
//
// As[4][128*128]: whole test-K staged once in prologue (64 KB).
// Bs[2][256*128]: train dbuf (64 KB), staged per step, 1-step prefetch,
// plain __syncthreads 2-phase (R4-verified schedule at 2 waves/SIMD).
//
// Swizzle f3(row) = (row&7)^((row>>3)&3), both sides (write source carries
// inverse; read XORs the same) -> conflict-free, k-order preserved per row.
// For frag reads row = {wr|wc}*64 + {mt|nt}*32 + l31 and the high bits are
// ===0 mod 4 after >>3, so f3 reduces to a per-thread constant
// fz = ((l31&7)^((l31>>3)&3))<<4.
//
// Exactness: fp8 screening only must keep the true top-5 within the top-24
// rescore set (quant sigma ~1.7 << 5th-vs-24th order-stat gap ~19); final
// answer is exact fp32 (kernel 3). All math/layout verified absmax=0 in
// R4/R6/R7/R9; this round changes geometry + swizzle width only.
// ===========================================================================
__global__ __launch_bounds__(512, 1) void knn_mfma_k(
    const unsigned char* __restrict__ Xtr8,   // fp8 e4m3 [N_TRAIN][DIM]
    const unsigned char* __restrict__ Xte8,   // fp8 e4m3 [N_TEST][DIM]
    const float* __restrict__ x2,
    unsigned* __restrict__ cand)              // [N_TEST][NCAND] u32 keys
{
    __shared__ __align__(16) unsigned char As[4][BTM * GBK];  // test, 64 KB
    __shared__ __align__(16) unsigned char Bs[2][BTN * GBK];  // train, 64 KB

    const int t    = threadIdx.x;
    const int lane = t & 63;
    const int w    = t >> 6;              // 0..7
    const int wr   = w >> 1, wc = w & 1;  // wr: train quarter (M), wc: test half (N)
    const int l31  = lane & 31;
    const int hi   = lane >> 5;
    const int fz   = (((l31 & 7) ^ ((l31 >> 3) & 3)) << 4);  // f3 for frag rows
    const int row0 = blockIdx.x * BTM;
    const int seg0 = blockIdx.y * SEG;

    unsigned top5[2][K_NN];
#pragma unroll
    for (int nt = 0; nt < 2; ++nt)
#pragma unroll
        for (int p = 0; p < K_NN; ++p) top5[nt][p] = 0xFFFFFFFFu;

    // ---- prologue: stage the ENTIRE test tile (4 k-phase buffers) once ----
    // chunk c = j*512 + t: buffer kb=c>>10, row=(c>>3)&127, phys slot c&7;
    // source slot = (c&7) ^ f3(row).  Dest base wave-uniform (j, w only).
#pragma unroll
    for (int j = 0; j < 8; ++j) {
        const int c  = j * 512 + t;
        const int rw = (c >> 3) & 127;
        const int f3 = (rw & 7) ^ ((rw >> 3) & 3);
        GLDS16(Xte8 + (size_t)(row0 + rw) * DIM + (c >> 10) * GBK
                    + (((c & 7) ^ f3) << 4),
               &As[0][0] + (j * 512 + w * 64) * 16);
    }

    // ---- train staging source offsets (4 chunks/thread/step) ----
    int offB[4];
#pragma unroll
    for (int j = 0; j < 4; ++j) {
        const int cs = j * 512 + t;
        const int gr = cs >> 3;                      // tile row 0..255
        const int f3 = (gr & 7) ^ ((gr >> 3) & 3);
        offB[j] = gr * DIM + (((cs ^ f3) & 7) << 4);
    }

    // stage train step s (col-tile s>>2, k-chunk s&3) into buffer b
    auto stageB = [&](int s, int b) {
        const unsigned char* bb =
            Xtr8 + (size_t)(seg0 + (s >> 2) * BTN) * DIM + (s & 3) * GBK;
#pragma unroll
        for (int j = 0; j < 4; ++j)
            GLDS16(bb + offB[j], &Bs[b][0] + (j * 512 + w * 64) * 16);
    };

    f32x16 acc[2][2];
    auto zero_acc = [&]() {
#pragma unroll
        for (int mt = 0; mt < 2; ++mt)
#pragma unroll
            for (int nt = 0; nt < 2; ++nt)
#pragma unroll
                for (int e = 0; e < 16; ++e) acc[mt][nt][e] = 0.f;
    };

    // per-ct register epilogue (identical math to R4/R7-verified)
    auto epilogue = [&](int ct) {
        const int col0 = seg0 + ct * BTN;
        f32x4 x2r[2][4];
#pragma unroll
        for (int mt = 0; mt < 2; ++mt)
#pragma unroll
            for (int g = 0; g < 4; ++g)
                x2r[mt][g] = *(const f32x4*)&x2[col0 + wr * 64 + mt * 32 + g * 8 + 4 * hi];
        const int cbase = ct * BTN + wr * 64;
#pragma unroll
        for (int nt = 0; nt < 2; ++nt) {
            float dv[2][16];
            float gm[2][4];
#pragma unroll
            for (int mt = 0; mt < 2; ++mt)
#pragma unroll
                for (int g = 0; g < 4; ++g) {
#pragma unroll
                    for (int i = 0; i < 4; ++i)
                        dv[mt][g * 4 + i] =
                            fmaf(-2.f, acc[mt][nt][g * 4 + i], x2r[mt][g][i]);
                    gm[mt][g] = fminf(fminf(dv[mt][g*4+0], dv[mt][g*4+1]),
                                      fminf(dv[mt][g*4+2], dv[mt][g*4+3]));
                }
            float dmin = fminf(
                fminf(fminf(gm[0][0], gm[0][1]), fminf(gm[0][2], gm[0][3])),
                fminf(fminf(gm[1][0], gm[1][1]), fminf(gm[1][2], gm[1][3])));
            if ((fmono(dmin) & KMASK) <= top5[nt][4]) {   // rare path
#pragma unroll
                for (int mt = 0; mt < 2; ++mt)
#pragma unroll
                    for (int g = 0; g < 4; ++g) {
                        if ((fmono(gm[mt][g]) & KMASK) <= top5[nt][4]) {
#pragma unroll
                            for (int i = 0; i < 4; ++i) {
                                unsigned key = (fmono(dv[mt][g * 4 + i]) & KMASK)
                                    | (unsigned)(cbase + mt * 32 + g * 8 + 4 * hi + i);
                                ins5u(key, top5[nt]);
                            }
                        }
                    }
            }
        }
    };

    stageB(0, 0);
    __syncthreads();   // drains test prologue + first train tile (vmcnt 0)

    zero_acc();

#pragma unroll 1
    for (int s = 0; s < NSTEP; ++s) {
        if (s + 1 < NSTEP) stageB(s + 1, (s + 1) & 1);  // prefetch next step

        const unsigned char* Ab = As[s & 3];   // test (resident all kernel)
        const unsigned char* Bb = Bs[s & 1];   // train
#pragma unroll
        for (int ks = 0; ks < 2; ++ks) {        // two K=64 halves
            const int xq = (ks * 64 + hi * 32) ^ fz;
            i32x8 trf[2], tef[2];
#pragma unroll
            for (int mt = 0; mt < 2; ++mt) {    // A = train rows (M)
                const unsigned char* p = &Bb[(wr * 64 + mt * 32 + l31) * GBK];
                int4 lo = *(const int4*)&p[xq];
                int4 hx = *(const int4*)&p[xq ^ 16];
                trf[mt] = (i32x8){lo.x, lo.y, lo.z, lo.w, hx.x, hx.y, hx.z, hx.w};
            }
#pragma unroll
            for (int nt = 0; nt < 2; ++nt) {    // B = test rows (N)
                const unsigned char* p = &Ab[(wc * 64 + nt * 32 + l31) * GBK];
                int4 lo = *(const int4*)&p[xq];
                int4 hx = *(const int4*)&p[xq ^ 16];
                tef[nt] = (i32x8){lo.x, lo.y, lo.z, lo.w, hx.x, hx.y, hx.z, hx.w};
            }
#pragma unroll
            for (int mt = 0; mt < 2; ++mt)
#pragma unroll
                for (int nt = 0; nt < 2; ++nt)
                    acc[mt][nt] = __builtin_amdgcn_mfma_scale_f32_32x32x64_f8f6f4(
                        trf[mt], tef[nt], acc[mt][nt],
                        0 /*A=e4m3*/, 0 /*B=e4m3*/,
                        0, 0x7F7F7F7F, 0, 0x7F7F7F7F /* scales = 2^0 */);
        }

        __syncthreads();   // drains prefetch (vmcnt) + frag reads (lgkm)

        if ((s & 3) == 3) {             // ct boundary (uniform branch)
            epilogue(s >> 2);
            zero_acc();
        }
    }

    // final merge through (now dead) test LDS: 512 thr x 10 keys = 20 KB
    __syncthreads();
    unsigned* MB = (unsigned*)&As[0][0];
#pragma unroll
    for (int nt = 0; nt < 2; ++nt)
#pragma unroll
        for (int p = 0; p < K_NN; ++p) MB[t * 10 + nt * K_NN + p] = top5[nt][p];
    __syncthreads();

    // one thread per test row, merge 8 sub-lists (wr 0..3 x hi 0..1) of 5
    if (t < BTM) {
        const int r   = t;
        const int mwc = r >> 6, mnt = (r >> 5) & 1, mn5 = r & 31;
        unsigned tp[K_NN];
#pragma unroll
        for (int p = 0; p < K_NN; ++p) tp[p] = 0xFFFFFFFFu;
#pragma unroll
        for (int w2 = 0; w2 < 4; ++w2)          // wr
#pragma unroll
            for (int h2 = 0; h2 < 2; ++h2) {    // hi
                const int tid = (w2 * 2 + mwc) * 64 + h2 * 32 + mn5;
                const unsigned* src = &MB[tid * 10 + mnt * K_NN];
#pragma unroll
                for (int p = 0; p < K_NN; ++p) ins5u(src[p], tp);
            }
        unsigned* cr = cand + (size_t)(row0 + r) * NCAND + blockIdx.y * K_NN;
#pragma unroll
        for (int p = 0; p < K_NN; ++p) cr[p] = tp[p];
    }
}

// ---------------------------------------------------------------------------
// Kernel 3: fused approx-merge (160 -> top-24) + exact fp32 rescore + vote.
// One wave per test row. cand entries are u32: trunc-dist(21) | col-local(11);
// global col = (entry_index/5)*SEG + col-local.
// ---------------------------------------------------------------------------
__global__ __launch_bounds__(256) void rescore_vote_k(
    const float* __restrict__ Xtr, const float* __restrict__ Xte,
    const float* __restrict__ x2,  const float* __restrict__ t2,
    const unsigned* __restrict__ cand,
    const int* __restrict__ y, int* __restrict__ out)
{
    int row  = blockIdx.x * 4 + (threadIdx.x >> 6);
    int lane = threadIdx.x & 63;
    const unsigned* cr = cand + (size_t)row * NCAND;

    auto expand = [](unsigned k, int e) -> unsigned long long {
        unsigned gcol = (unsigned)(e / K_NN) * SEG + (k & 0x7FFu);
        return ((unsigned long long)k << 32) | gcol;
    };
    unsigned long long c0 = expand(cr[lane], lane);
    unsigned long long c1 = expand(cr[64 + lane], 64 + lane);
    unsigned long long c2 = (lane < NCAND - 128)
                          ? expand(cr[128 + lane], 128 + lane) : ~0ull;

    // iteratively extract the NRES smallest approx keys (all lanes get cols)
    unsigned cols[NRES];
#pragma unroll 1
    for (int i = 0; i < NRES; ++i) {
        unsigned long long m = c0 < c1 ? c0 : c1;
        m = c2 < m ? c2 : m;
#pragma unroll
        for (int off = 32; off > 0; off >>= 1) {
            unsigned long long o = __shfl_xor(m, off, 64);
            m = o < m ? o : m;
        }
        cols[i] = (unsigned)(m & 0xffffffffu);
        if (c0 == m) c0 = ~0ull;
        if (c1 == m) c1 = ~0ull;
        if (c2 == m) c2 = ~0ull;
    }

    // exact fp32 rescore of the NRES candidates
    const float4* te = (const float4*)(Xte + (size_t)row * DIM);
    float4 e0 = te[lane * 2], e1 = te[lane * 2 + 1];
    float t2r = t2[row];
    float d2s[NRES];
#pragma unroll 4
    for (int i = 0; i < NRES; ++i) {
        const float4* tr = (const float4*)(Xtr + (size_t)cols[i] * DIM);
        float4 p = tr[lane * 2], q = tr[lane * 2 + 1];
        float s = e0.x * p.x;
        s = fmaf(e0.y, p.y, s); s = fmaf(e0.z, p.z, s); s = fmaf(e0.w, p.w, s);
        s = fmaf(e1.x, q.x, s); s = fmaf(e1.y, q.y, s);
        s = fmaf(e1.z, q.z, s); s = fmaf(e1.w, q.w, s);
#pragma unroll
        for (int off = 32; off > 0; off >>= 1) s += __shfl_xor(s, off, 64);
        d2s[i] = fmaxf(t2r + x2[cols[i]] - 2.0f * s, 0.0f);
    }

    // exact top-5 (all lanes redundantly) + mode vote on lane 0
    unsigned long long top[K_NN];
#pragma unroll
    for (int p = 0; p < K_NN; ++p) top[p] = ~0ull;
#pragma unroll
    for (int i = 0; i < NRES; ++i)
        ins5(((unsigned long long)__float_as_uint(d2s[i]) << 32) | cols[i], top);

    if (lane == 0) {
        int labs[K_NN];
#pragma unroll
        for (int p = 0; p < K_NN; ++p) labs[p] = y[(unsigned)(top[p] & 0xffffffffu)];
        int bestLab = 0x7fffffff, bestCnt = 0;
#pragma unroll
        for (int p = 0; p < K_NN; ++p) {
            int cnt = 0;
#pragma unroll
            for (int q = 0; q < K_NN; ++q) cnt += (labs[q] == labs[p]) ? 1 : 0;
            if (cnt > bestCnt || (cnt == bestCnt && labs[p] < bestLab)) {
                bestCnt = cnt; bestLab = labs[p];
            }
        }
        out[row] = bestLab;
    }
}

// ===========================================================================
// Fallback fp32 path (round-1, verified) in case ws_size is too small.
// ===========================================================================
#define FTM 64
#define FTN 128
#define FBK 16
#define FSEG (N_TRAIN / 8)

__global__ __launch_bounds__(256) void knn_tile_k(
    const float* __restrict__ Xtr, const float* __restrict__ Xte,
    const float* __restrict__ x2,  const float* __restrict__ t2,
    unsigned long long* __restrict__ cand)
{
    __shared__ float As[FBK][FTM];
    __shared__ float Bs[FBK][FTN];
    __shared__ unsigned long long MB[FTM][16 * K_NN];

    const int t   = threadIdx.x;
    const int ty  = t >> 4;
    const int tx  = t & 15;
    const int row0 = blockIdx.x * FTM;
    const int seg0 = blockIdx.y * FSEG;

    float t2r[4];
#pragma unroll
    for (int j = 0; j < 4; ++j) t2r[j] = t2[row0 + ty * 4 + j];

    unsigned long long top[4][K_NN];
#pragma unroll
    for (int j = 0; j < 4; ++j)
#pragma unroll
        for (int p = 0; p < K_NN; ++p) top[j][p] = ~0ull;

    const int srow = t >> 2;
    const int skq  = (t & 3) * 4;

    for (int ct = 0; ct < FSEG / FTN; ++ct) {
        const int col0 = seg0 + ct * FTN;
        float acc[4][8] = {};

        for (int k0 = 0; k0 < DIM; k0 += FBK) {
            float4 av  = *(const float4*)(Xte + (size_t)(row0 + srow) * DIM + k0 + skq);
            float4 bv0 = *(const float4*)(Xtr + (size_t)(col0 + srow) * DIM + k0 + skq);
            float4 bv1 = *(const float4*)(Xtr + (size_t)(col0 + 64 + srow) * DIM + k0 + skq);
            __syncthreads();
            As[skq + 0][srow] = av.x;  As[skq + 1][srow] = av.y;
            As[skq + 2][srow] = av.z;  As[skq + 3][srow] = av.w;
            Bs[skq + 0][srow] = bv0.x; Bs[skq + 1][srow] = bv0.y;
            Bs[skq + 2][srow] = bv0.z; Bs[skq + 3][srow] = bv0.w;
            Bs[skq + 0][srow + 64] = bv1.x; Bs[skq + 1][srow + 64] = bv1.y;
            Bs[skq + 2][srow + 64] = bv1.z; Bs[skq + 3][srow + 64] = bv1.w;
            __syncthreads();

#pragma unroll
            for (int k = 0; k < FBK; ++k) {
                float4 a  = *(const float4*)&As[k][ty * 4];
                float4 b0 = *(const float4*)&Bs[k][tx * 8];
                float4 b1 = *(const float4*)&Bs[k][tx * 8 + 4];
                float a4[4] = {a.x, a.y, a.z, a.w};
                float b8[8] = {b0.x, b0.y, b0.z, b0.w, b1.x, b1.y, b1.z, b1.w};
#pragma unroll
                for (int j = 0; j < 4; ++j)
#pragma unroll
                    for (int l = 0; l < 8; ++l)
                        acc[j][l] = fmaf(a4[j], b8[l], acc[j][l]);
            }
        }

#pragma unroll
        for (int j = 0; j < 4; ++j) {
#pragma unroll
            for (int l = 0; l < 8; ++l) {
                int col = col0 + tx * 8 + l;
                float d2 = fmaxf(t2r[j] + x2[col] - 2.0f * acc[j][l], 0.0f);
                unsigned long long key =
                    ((unsigned long long)__float_as_uint(d2) << 32) | (unsigned)col;
                ins5(key, top[j]);
            }
        }
    }

#pragma unroll
    for (int j = 0; j < 4; ++j)
#pragma unroll
        for (int p = 0; p < K_NN; ++p)
            MB[ty * 4 + j][tx * K_NN + p] = top[j][p];
    __syncthreads();

    if (t < FTM) {
        unsigned long long last = 0;
        for (int p = 0; p < K_NN; ++p) {
            unsigned long long best = ~0ull;
            for (int q = 0; q < 16 * K_NN; ++q) {
                unsigned long long v = MB[t][q];
                if (v > last && v < best) best = v;
            }
            cand[(size_t)(row0 + t) * 40 + blockIdx.y * K_NN + p] = best;
            last = best;
        }
    }
}

__global__ __launch_bounds__(256) void knn_final_k(
    const unsigned long long* __restrict__ cand,
    const int* __restrict__ y, int* __restrict__ out)
{
    int r = blockIdx.x * 256 + threadIdx.x;
    if (r >= N_TEST) return;
    const unsigned long long* c = cand + (size_t)r * 40;

    unsigned long long top[K_NN];
#pragma unroll
    for (int p = 0; p < K_NN; ++p) top[p] = ~0ull;
#pragma unroll
    for (int i = 0; i < 40; ++i) ins5(c[i], top);

    int labs[K_NN];
#pragma unroll
    for (int p = 0; p < K_NN; ++p) labs[p] = y[(unsigned)(top[p] & 0xffffffffu)];

    int bestLab = 0x7fffffff, bestCnt = 0;
#pragma unroll
    for (int p = 0; p < K_NN; ++p) {
        int cnt = 0;
#pragma unroll
        for (int q = 0; q < K_NN; ++q) cnt += (labs[q] == labs[p]) ? 1 : 0;
        if (cnt > bestCnt || (cnt == bestCnt && labs[p] < bestLab)) {
            bestCnt = cnt; bestLab = labs[p];
        }
    }
    out[r] = bestLab;
}

// ---------------------------------------------------------------------------
// Workspace layout (fp8 path), bytes (NEED unchanged — known-good size):
//   [0,        262144)   x2     : 65536 f32
//   [262144,   278528)   t2     : 4096 f32
//   [278528,  2899968)   cand   : 4096 * 160 u32
//   [3145728, 5242880)   Xte_f8 : 4096*512  e4m3 (2 MB)
//   [7340032, 40894464)  Xtr_f8 : 65536*512 e4m3 (32 MB)
// ---------------------------------------------------------------------------
extern "C" void kernel_launch(void* const* d_in, const int* in_sizes, int n_in,
                              void* d_out, int out_size, void* d_ws, size_t ws_size,
                              hipStream_t stream) {
    const float* Xtr = (const float*)d_in[0];
    const float* Xte = (const float*)d_in[1];
    const int*   y   = (const int*)d_in[2];
    int* out = (int*)d_out;

    char* ws = (char*)d_ws;
    float* x2 = (float*)ws;
    float* t2 = (float*)(ws + 262144);

    const size_t NEED = 74448896;

    if (ws_size >= NEED) {
        unsigned* cand = (unsigned*)(ws + 278528);
        unsigned char* Xte8 = (unsigned char*)(ws + 3145728);
        unsigned char* Xtr8 = (unsigned char*)(ws + 7340032);

        cvtnorm8_k<<<N_TRAIN / 4, 256, 0, stream>>>(Xtr, Xtr8, x2, N_TRAIN);
        cvtnorm8_k<<<N_TEST / 4, 256, 0, stream>>>(Xte, Xte8, t2, N_TEST);

        knn_mfma_k<<<dim3(N_TEST / BTM, NSEG), 512, 0, stream>>>(Xtr8, Xte8, x2, cand);
        rescore_vote_k<<<N_TEST / 4, 256, 0, stream>>>(Xtr, Xte, x2, t2, cand, y, out);
    } else {
        // fp32 fallback (round-1 verified path); cand here is [N_TEST][40] u64
        unsigned long long* cand = (unsigned long long*)(ws + 278528);
        norms_k<<<N_TRAIN / 4, 256, 0, stream>>>(Xtr, x2, N_TRAIN);
        norms_k<<<N_TEST / 4, 256, 0, stream>>>(Xte, t2, N_TEST);
        knn_tile_k<<<dim3(N_TEST / FTM, 8), 256, 0, stream>>>(Xtr, Xte, x2, t2, cand);
        knn_final_k<<<N_TEST / 256, 256, 0, stream>>>(cand, y, out);
    }
}

// Round 11
// 481.673 us; speedup vs baseline: 1.6776x; 1.1467x over previous
//
#include <hip/hip_runtime.h>
#include <cstdint>

// Problem constants (fixed by the reference)
#define N_TRAIN 65536
#define N_TEST  4096
#define DIM     512
#define K_NN    5
#define NSEG    32
#define SEG     (N_TRAIN / NSEG)   // 2048 train cols per segment

// fp8 32x32x64 scaled-MFMA path. C/D layout (measured, dtype-independent):
// col=lane&31 (test row), row=(reg&3)+8*(reg>>2)+4*(lane>>5) (train col).
//
// ROUND-11 STRUCTURE (R4's verified 2-phase at 4 waves/SIMD):
//   Cross-round data: perf ~ resident waves/CU (R9 4w: 619us; R4/R7/R10
//   7-8w: 310-353us). The ~3x gap between measured step time and component
//   maxima is exposed latency -> fill with TLP. This config: 512-thr blocks
//   on the R4 tile (128 test x 128 train, As+Bs dbuf = 64 KB) -> 2 blocks/CU
//   = 16 waves/CU = 4/SIMD. Per-wave tile halves to 1x2 of 32x32 (acc 32
//   regs, frags 24) so the register budget fits 4 waves/SIMD (<=128 total,
//   enforced by __launch_bounds__(512,4)).
//
// CONFLICT-FREE swizzle f3(row) = (row&7) ^ ((row>>3)&3) (R10-verified:
// conflicts 1.69e7 -> 1.6e5). Both-sides rule: gload_lds writes linearly,
// SOURCE carries the inverse; XOR touches byte-bits 4..6 only -> 16B chunks
// intact, per-row logical k order preserved -> dot product exact.
#define BTM 128      // test rows per block (N dim)
#define BTN 128      // train cols per tile (M dim)
#define GBK 128      // K bytes (fp8 elems) consumed per step (2 MFMA K-halves)
#define NCAND (NSEG * K_NN)                 // 160 u32 candidates per test row
#define NRES  24                            // exactly-rescored candidates
#define NSTEP ((SEG / BTN) * (DIM / GBK))   // 16 col-tiles * 4 k-steps = 64
#define KMASK 0xFFFFF800u                   // 21-bit trunc dist | 11-bit col

typedef float f32x4  __attribute__((ext_vector_type(4)));
typedef float f32x16 __attribute__((ext_vector_type(16)));
typedef int   i32x8  __attribute__((ext_vector_type(8)));

#define GLDS16(g, l)                                                          \
    __builtin_amdgcn_global_load_lds(                                         \
        (__attribute__((address_space(1))) void*)(g),                         \
        (__attribute__((address_space(3))) void*)(l), 16, 0, 0)

// ---------------------------------------------------------------------------
// fp32 -> OCP e4m3fn (RNE, saturating). SW fallback bit-exact, header-free.
// ---------------------------------------------------------------------------
__device__ inline unsigned f2e4m3_sw(float x) {
    float ax = fabsf(x);
    unsigned sgn = (__float_as_uint(x) >> 31) << 7;
    if (ax != ax) return sgn | 0x7Fu;            // NaN
    if (ax >= 448.0f) return sgn | 0x7Eu;        // saturate to 448
    int ebits = (int)((__float_as_uint(ax) >> 23) & 0xFF);
    int e = ebits - 127;
    int shift = (e < -6 ? -6 : e) - 3;           // e4m3 quantum exponent
    float q = exp2f((float)shift);
    float r = rintf(ax / q) * q;                 // RNE onto the e4m3 grid
    if (r >= 448.0f) return sgn | 0x7Eu;
    if (r == 0.0f) return sgn;
    unsigned ru = __float_as_uint(r);
    int re = (int)((ru >> 23) & 0xFF) - 127;
    if (re < -6) {                               // e4m3 subnormal: k * 2^-9
        unsigned k = (unsigned)(r * 512.0f);
        return sgn | k;
    }
    unsigned rm = (ru >> 20) & 0x7u;
    return sgn | ((unsigned)(re + 7) << 3) | rm;
}

__device__ inline unsigned pk4_fp8(float x0, float x1, float x2, float x3) {
#if __has_builtin(__builtin_amdgcn_cvt_pk_fp8_f32)
    unsigned r = (unsigned)__builtin_amdgcn_cvt_pk_fp8_f32(x0, x1, 0, 0);
    r = (unsigned)__builtin_amdgcn_cvt_pk_fp8_f32(x2, x3, (int)r, 1);
    return r;
#else
    return f2e4m3_sw(x0) | (f2e4m3_sw(x1) << 8) |
           (f2e4m3_sw(x2) << 16) | (f2e4m3_sw(x3) << 24);
#endif
}

// ---------------------------------------------------------------------------
// Kernel 1: fused fp8(e4m3) convert + squared L2 row norms. One wave per row.
// ---------------------------------------------------------------------------
__global__ __launch_bounds__(256) void cvtnorm8_k(const float* __restrict__ in,
                                                  unsigned char* __restrict__ outb,
                                                  float* __restrict__ outn,
                                                  int nrows) {
    int row  = blockIdx.x * 4 + (threadIdx.x >> 6);
    int lane = threadIdx.x & 63;
    if (row >= nrows) return;
    const float4* p = (const float4*)(in + (size_t)row * DIM) + lane * 2;
    float4 a = p[0], b = p[1];
    float s = a.x*a.x + a.y*a.y + a.z*a.z + a.w*a.w
            + b.x*b.x + b.y*b.y + b.z*b.z + b.w*b.w;
    uint2 v;
    v.x = pk4_fp8(a.x, a.y, a.z, a.w);
    v.y = pk4_fp8(b.x, b.y, b.z, b.w);
    *((uint2*)(outb + (size_t)row * DIM) + lane) = v;
#pragma unroll
    for (int off = 32; off > 0; off >>= 1) s += __shfl_xor(s, off, 64);
    if (lane == 0) outn[row] = s;
}

// plain norms (fallback path)
__global__ __launch_bounds__(256) void norms_k(const float* __restrict__ X,
                                               float* __restrict__ out,
                                               int nrows) {
    int row  = blockIdx.x * 4 + (threadIdx.x >> 6);
    int lane = threadIdx.x & 63;
    if (row >= nrows) return;
    const float4* xp = (const float4*)(X + (size_t)row * DIM);
    float4 a = xp[lane];
    float4 b = xp[lane + 64];
    float s = a.x*a.x + a.y*a.y + a.z*a.z + a.w*a.w
            + b.x*b.x + b.y*b.y + b.z*b.z + b.w*b.w;
#pragma unroll
    for (int off = 32; off > 0; off >>= 1) s += __shfl_down(s, off, 64);
    if (lane == 0) out[row] = s;
}

// ---------------------------------------------------------------------------
// top-5 insertion (sorted ascending)
// ---------------------------------------------------------------------------
__device__ inline void ins5(unsigned long long key, unsigned long long* top) {
    if (key < top[4]) {
        unsigned long long k0 = top[0], k1 = top[1], k2 = top[2], k3 = top[3];
        top[0] = key < k0 ? key : k0;
        top[1] = key < k0 ? k0 : (key < k1 ? key : k1);
        top[2] = key < k1 ? k1 : (key < k2 ? key : k2);
        top[3] = key < k2 ? k2 : (key < k3 ? key : k3);
        top[4] = key < k3 ? k3 : key;
    }
}

__device__ inline void ins5u(unsigned key, unsigned* top) {
    if (key < top[4]) {
        unsigned k0 = top[0], k1 = top[1], k2 = top[2], k3 = top[3];
        top[0] = key < k0 ? key : k0;
        top[1] = key < k0 ? k0 : (key < k1 ? key : k1);
        top[2] = key < k1 ? k1 : (key < k2 ? key : k2);
        top[3] = key < k2 ? k2 : (key < k3 ? key : k3);
        top[4] = key < k3 ? k3 : key;
    }
}

// order-preserving float -> uint map (handles negatives)
__device__ inline unsigned fmono(float v) {
    unsigned u = __float_as_uint(v);
    return (u & 0x80000000u) ? ~u : (u | 0x80000000u);
}

// ===========================================================================
// Kernel 2: fp8 32x32x64 scaled-MFMA distance GEMM (R11 structure).
// 512 thr = 8 waves: wr = w>>1 in 0..3 (32-train-row strip), wc = w&1
// (64-test-row half); per wave 1x2 tiles of 32x32 (acc[2] f32x16 = 32 regs).
//
// As[2][128*128B] test dbuf + Bs[2][128*128B] train dbuf = 64 KB -> 2
// blocks/CU = 16 waves/CU = 4 waves/SIMD. Plain 2-phase __syncthreads
// schedule (R4-verified); both tiles staged per step, 1-step prefetch,
// 2+2 chunks/thread via global_load_lds with f3-swizzled source.
//
// Frag rows = strip*32 + l31, so f3 reduces to the per-thread constant
// fz = ((l31&7)^((l31>>3)&3))<<4 (verified derivation R10).
//
// Exactness: fp8 screening only must keep the true top-5 within the top-24
// rescore set (quant sigma ~1.7 << 5th-vs-24th order-stat gap ~19); final
// answer is exact fp32 (kernel 3). All math/layout verified absmax=0 in
// R4/R6/R7/R9/R10; this round changes wave geometry/occupancy only.
// ===========================================================================
__global__ __launch_bounds__(512, 4) void knn_mfma_k(
    const unsigned char* __restrict__ Xtr8,   // fp8 e4m3 [N_TRAIN][DIM]
    const unsigned char* __restrict__ Xte8,   // fp8 e4m3 [N_TEST][DIM]
    const float* __restrict__ x2,
    unsigned* __restrict__ cand)              // [N_TEST][NCAND] u32 keys
{
    __shared__ __align__(16) unsigned char As[2][BTM * GBK];  // test,  32 KB
    __shared__ __align__(16) unsigned char Bs[2][BTN * GBK];  // train, 32 KB

    const int t    = threadIdx.x;
    const int lane = t & 63;
    const int w    = t >> 6;              // 0..7
    const int wr   = w >> 1, wc = w & 1;  // wr: 32-train strip, wc: 64-test half
    const int l31  = lane & 31;
    const int hi   = lane >> 5;
    const int fz   = (((l31 & 7) ^ ((l31 >> 3) & 3)) << 4);  // f3 for frag rows
    const int row0 = blockIdx.x * BTM;
    const int seg0 = blockIdx.y * SEG;

    unsigned top5[2][K_NN];
#pragma unroll
    for (int nt = 0; nt < 2; ++nt)
#pragma unroll
        for (int p = 0; p < K_NN; ++p) top5[nt][p] = 0xFFFFFFFFu;

    // ---- staging source offsets (2 chunks/thread per tile; both tiles are
    // 128 rows x 128 B so the offsets are shared): chunk cs = j*512 + t ->
    // row gr = cs>>3 (0..127), phys slot cs&7, source slot (cs&7)^f3(gr).
    int off[2];
#pragma unroll
    for (int j = 0; j < 2; ++j) {
        const int cs = j * 512 + t;
        const int gr = cs >> 3;
        const int f3 = (gr & 7) ^ ((gr >> 3) & 3);
        off[j] = gr * DIM + (((cs ^ f3) & 7) << 4);
    }

    // stage step s (col-tile s>>2, k-chunk s&3) into buffer b (test + train)
    auto stage = [&](int s, int b) {
        const int k0 = (s & 3) * GBK;
        const unsigned char* ab = Xte8 + (size_t)row0 * DIM + k0;
        const unsigned char* bb =
            Xtr8 + (size_t)(seg0 + (s >> 2) * BTN) * DIM + k0;
#pragma unroll
        for (int j = 0; j < 2; ++j) {
            const int ldsb = (j * 512 + w * 64) * 16;   // wave-uniform dest base
            GLDS16(ab + off[j], &As[b][ldsb]);
            GLDS16(bb + off[j], &Bs[b][ldsb]);
        }
    };

    f32x16 acc[2];
    auto zero_acc = [&]() {
#pragma unroll
        for (int nt = 0; nt < 2; ++nt)
#pragma unroll
            for (int e = 0; e < 16; ++e) acc[nt][e] = 0.f;
    };

    // per-ct register epilogue: per nt (one test row/lane), 16 train cols
    // of the wave's 32-strip (cols g*8 + 4*hi + i).
    auto epilogue = [&](int ct) {
        const int col0 = seg0 + ct * BTN;
        f32x4 x2r[4];
#pragma unroll
        for (int g = 0; g < 4; ++g)
            x2r[g] = *(const f32x4*)&x2[col0 + wr * 32 + g * 8 + 4 * hi];
        const int cbase = ct * BTN + wr * 32;
#pragma unroll
        for (int nt = 0; nt < 2; ++nt) {
            float dv[16];
            float gm[4];
#pragma unroll
            for (int g = 0; g < 4; ++g) {
#pragma unroll
                for (int i = 0; i < 4; ++i)
                    dv[g * 4 + i] = fmaf(-2.f, acc[nt][g * 4 + i], x2r[g][i]);
                gm[g] = fminf(fminf(dv[g*4+0], dv[g*4+1]),
                              fminf(dv[g*4+2], dv[g*4+3]));
            }
            float dmin = fminf(fminf(gm[0], gm[1]), fminf(gm[2], gm[3]));
            if ((fmono(dmin) & KMASK) <= top5[nt][4]) {   // rare path
#pragma unroll
                for (int g = 0; g < 4; ++g) {
                    if ((fmono(gm[g]) & KMASK) <= top5[nt][4]) {
#pragma unroll
                        for (int i = 0; i < 4; ++i) {
                            unsigned key = (fmono(dv[g * 4 + i]) & KMASK)
                                | (unsigned)(cbase + g * 8 + 4 * hi + i);
                            ins5u(key, top5[nt]);
                        }
                    }
                }
            }
        }
    };

    stage(0, 0);
    __syncthreads();   // drains first stage (vmcnt 0)

    zero_acc();

#pragma unroll 1
    for (int s = 0; s < NSTEP; ++s) {
        if (s + 1 < NSTEP) stage(s + 1, (s + 1) & 1);  // prefetch next step

        const unsigned char* Ab = As[s & 1];   // test
        const unsigned char* Bb = Bs[s & 1];   // train
#pragma unroll
        for (int ks = 0; ks < 2; ++ks) {        // two K=64 halves
            const int xq = (ks * 64 + hi * 32) ^ fz;
            i32x8 trf, tef[2];
            {   // A = train rows (M): this wave's 32-strip
                const unsigned char* p = &Bb[(wr * 32 + l31) * GBK];
                int4 lo = *(const int4*)&p[xq];
                int4 hx = *(const int4*)&p[xq ^ 16];
                trf = (i32x8){lo.x, lo.y, lo.z, lo.w, hx.x, hx.y, hx.z, hx.w};
            }
#pragma unroll
            for (int nt = 0; nt < 2; ++nt) {    // B = test rows (N)
                const unsigned char* p = &Ab[(wc * 64 + nt * 32 + l31) * GBK];
                int4 lo = *(const int4*)&p[xq];
                int4 hx = *(const int4*)&p[xq ^ 16];
                tef[nt] = (i32x8){lo.x, lo.y, lo.z, lo.w, hx.x, hx.y, hx.z, hx.w};
            }
#pragma unroll
            for (int nt = 0; nt < 2; ++nt)
                acc[nt] = __builtin_amdgcn_mfma_scale_f32_32x32x64_f8f6f4(
                    trf, tef[nt], acc[nt],
                    0 /*A=e4m3*/, 0 /*B=e4m3*/,
                    0, 0x7F7F7F7F, 0, 0x7F7F7F7F /* scales = 2^0 */);
        }

        __syncthreads();   // drains prefetch (vmcnt) + frag reads (lgkm)

        if ((s & 3) == 3) {             // ct boundary (uniform branch)
            epilogue(s >> 2);
            zero_acc();
        }
    }

    // final merge through (now dead) staging LDS: 512 thr x 10 keys = 20 KB
    __syncthreads();
    unsigned* MB = (unsigned*)&As[0][0];
#pragma unroll
    for (int nt = 0; nt < 2; ++nt)
#pragma unroll
        for (int p = 0; p < K_NN; ++p) MB[t * 10 + nt * K_NN + p] = top5[nt][p];
    __syncthreads();

    // one thread per test row, merge 8 sub-lists (wr 0..3 x hi 0..1) of 5
    if (t < BTM) {
        const int r   = t;
        const int mwc = r >> 6, mnt = (r >> 5) & 1, mn5 = r & 31;
        unsigned tp[K_NN];
#pragma unroll
        for (int p = 0; p < K_NN; ++p) tp[p] = 0xFFFFFFFFu;
#pragma unroll
        for (int w2 = 0; w2 < 4; ++w2)          // wr
#pragma unroll
            for (int h2 = 0; h2 < 2; ++h2) {    // hi
                const int tid = (w2 * 2 + mwc) * 64 + h2 * 32 + mn5;
                const unsigned* src = &MB[tid * 10 + mnt * K_NN];
#pragma unroll
                for (int p = 0; p < K_NN; ++p) ins5u(src[p], tp);
            }
        unsigned* cr = cand + (size_t)(row0 + r) * NCAND + blockIdx.y * K_NN;
#pragma unroll
        for (int p = 0; p < K_NN; ++p) cr[p] = tp[p];
    }
}

// ---------------------------------------------------------------------------
// Kernel 3: fused approx-merge (160 -> top-24) + exact fp32 rescore + vote.
// One wave per test row. cand entries are u32: trunc-dist(21) | col-local(11);
// global col = (entry_index/5)*SEG + col-local.
// ---------------------------------------------------------------------------
__global__ __launch_bounds__(256) void rescore_vote_k(
    const float* __restrict__ Xtr, const float* __restrict__ Xte,
    const float* __restrict__ x2,  const float* __restrict__ t2,
    const unsigned* __restrict__ cand,
    const int* __restrict__ y, int* __restrict__ out)
{
    int row  = blockIdx.x * 4 + (threadIdx.x >> 6);
    int lane = threadIdx.x & 63;
    const unsigned* cr = cand + (size_t)row * NCAND;

    auto expand = [](unsigned k, int e) -> unsigned long long {
        unsigned gcol = (unsigned)(e / K_NN) * SEG + (k & 0x7FFu);
        return ((unsigned long long)k << 32) | gcol;
    };
    unsigned long long c0 = expand(cr[lane], lane);
    unsigned long long c1 = expand(cr[64 + lane], 64 + lane);
    unsigned long long c2 = (lane < NCAND - 128)
                          ? expand(cr[128 + lane], 128 + lane) : ~0ull;

    // iteratively extract the NRES smallest approx keys (all lanes get cols)
    unsigned cols[NRES];
#pragma unroll 1
    for (int i = 0; i < NRES; ++i) {
        unsigned long long m = c0 < c1 ? c0 : c1;
        m = c2 < m ? c2 : m;
#pragma unroll
        for (int off = 32; off > 0; off >>= 1) {
            unsigned long long o = __shfl_xor(m, off, 64);
            m = o < m ? o : m;
        }
        cols[i] = (unsigned)(m & 0xffffffffu);
        if (c0 == m) c0 = ~0ull;
        if (c1 == m) c1 = ~0ull;
        if (c2 == m) c2 = ~0ull;
    }

    // exact fp32 rescore of the NRES candidates
    const float4* te = (const float4*)(Xte + (size_t)row * DIM);
    float4 e0 = te[lane * 2], e1 = te[lane * 2 + 1];
    float t2r = t2[row];
    float d2s[NRES];
#pragma unroll 4
    for (int i = 0; i < NRES; ++i) {
        const float4* tr = (const float4*)(Xtr + (size_t)cols[i] * DIM);
        float4 p = tr[lane * 2], q = tr[lane * 2 + 1];
        float s = e0.x * p.x;
        s = fmaf(e0.y, p.y, s); s = fmaf(e0.z, p.z, s); s = fmaf(e0.w, p.w, s);
        s = fmaf(e1.x, q.x, s); s = fmaf(e1.y, q.y, s);
        s = fmaf(e1.z, q.z, s); s = fmaf(e1.w, q.w, s);
#pragma unroll
        for (int off = 32; off > 0; off >>= 1) s += __shfl_xor(s, off, 64);
        d2s[i] = fmaxf(t2r + x2[cols[i]] - 2.0f * s, 0.0f);
    }

    // exact top-5 (all lanes redundantly) + mode vote on lane 0
    unsigned long long top[K_NN];
#pragma unroll
    for (int p = 0; p < K_NN; ++p) top[p] = ~0ull;
#pragma unroll
    for (int i = 0; i < NRES; ++i)
        ins5(((unsigned long long)__float_as_uint(d2s[i]) << 32) | cols[i], top);

    if (lane == 0) {
        int labs[K_NN];
#pragma unroll
        for (int p = 0; p < K_NN; ++p) labs[p] = y[(unsigned)(top[p] & 0xffffffffu)];
        int bestLab = 0x7fffffff, bestCnt = 0;
#pragma unroll
        for (int p = 0; p < K_NN; ++p) {
            int cnt = 0;
#pragma unroll
            for (int q = 0; q < K_NN; ++q) cnt += (labs[q] == labs[p]) ? 1 : 0;
            if (cnt > bestCnt || (cnt == bestCnt && labs[p] < bestLab)) {
                bestCnt = cnt; bestLab = labs[p];
            }
        }
        out[row] = bestLab;
    }
}

// ===========================================================================
// Fallback fp32 path (round-1, verified) in case ws_size is too small.
// ===========================================================================
#define FTM 64
#define FTN 128
#define FBK 16
#define FSEG (N_TRAIN / 8)

__global__ __launch_bounds__(256) void knn_tile_k(
    const float* __restrict__ Xtr, const float* __restrict__ Xte,
    const float* __restrict__ x2,  const float* __restrict__ t2,
    unsigned long long* __restrict__ cand)
{
    __shared__ float As[FBK][FTM];
    __shared__ float Bs[FBK][FTN];
    __shared__ unsigned long long MB[FTM][16 * K_NN];

    const int t   = threadIdx.x;
    const int ty  = t >> 4;
    const int tx  = t & 15;
    const int row0 = blockIdx.x * FTM;
    const int seg0 = blockIdx.y * FSEG;

    float t2r[4];
#pragma unroll
    for (int j = 0; j < 4; ++j) t2r[j] = t2[row0 + ty * 4 + j];

    unsigned long long top[4][K_NN];
#pragma unroll
    for (int j = 0; j < 4; ++j)
#pragma unroll
        for (int p = 0; p < K_NN; ++p) top[j][p] = ~0ull;

    const int srow = t >> 2;
    const int skq  = (t & 3) * 4;

    for (int ct = 0; ct < FSEG / FTN; ++ct) {
        const int col0 = seg0 + ct * FTN;
        float acc[4][8] = {};

        for (int k0 = 0; k0 < DIM; k0 += FBK) {
            float4 av  = *(const float4*)(Xte + (size_t)(row0 + srow) * DIM + k0 + skq);
            float4 bv0 = *(const float4*)(Xtr + (size_t)(col0 + srow) * DIM + k0 + skq);
            float4 bv1 = *(const float4*)(Xtr + (size_t)(col0 + 64 + srow) * DIM + k0 + skq);
            __syncthreads();
            As[skq + 0][srow] = av.x;  As[skq + 1][srow] = av.y;
            As[skq + 2][srow] = av.z;  As[skq + 3][srow] = av.w;
            Bs[skq + 0][srow] = bv0.x; Bs[skq + 1][srow] = bv0.y;
            Bs[skq + 2][srow] = bv0.z; Bs[skq + 3][srow] = bv0.w;
            Bs[skq + 0][srow + 64] = bv1.x; Bs[skq + 1][srow + 64] = bv1.y;
            Bs[skq + 2][srow + 64] = bv1.z; Bs[skq + 3][srow + 64] = bv1.w;
            __syncthreads();

#pragma unroll
            for (int k = 0; k < FBK; ++k) {
                float4 a  = *(const float4*)&As[k][ty * 4];
                float4 b0 = *(const float4*)&Bs[k][tx * 8];
                float4 b1 = *(const float4*)&Bs[k][tx * 8 + 4];
                float a4[4] = {a.x, a.y, a.z, a.w};
                float b8[8] = {b0.x, b0.y, b0.z, b0.w, b1.x, b1.y, b1.z, b1.w};
#pragma unroll
                for (int j = 0; j < 4; ++j)
#pragma unroll
                    for (int l = 0; l < 8; ++l)
                        acc[j][l] = fmaf(a4[j], b8[l], acc[j][l]);
            }
        }

#pragma unroll
        for (int j = 0; j < 4; ++j) {
#pragma unroll
            for (int l = 0; l < 8; ++l) {
                int col = col0 + tx * 8 + l;
                float d2 = fmaxf(t2r[j] + x2[col] - 2.0f * acc[j][l], 0.0f);
                unsigned long long key =
                    ((unsigned long long)__float_as_uint(d2) << 32) | (unsigned)col;
                ins5(key, top[j]);
            }
        }
    }

#pragma unroll
    for (int j = 0; j < 4; ++j)
#pragma unroll
        for (int p = 0; p < K_NN; ++p)
            MB[ty * 4 + j][tx * K_NN + p] = top[j][p];
    __syncthreads();

    if (t < FTM) {
        unsigned long long last = 0;
        for (int p = 0; p < K_NN; ++p) {
            unsigned long long best = ~0ull;
            for (int q = 0; q < 16 * K_NN; ++q) {
                unsigned long long v = MB[t][q];
                if (v > last && v < best) best = v;
            }
            cand[(size_t)(row0 + t) * 40 + blockIdx.y * K_NN + p] = best;
            last = best;
        }
    }
}

__global__ __launch_bounds__(256) void knn_final_k(
    const unsigned long long* __restrict__ cand,
    const int* __restrict__ y, int* __restrict__ out)
{
    int r = blockIdx.x * 256 + threadIdx.x;
    if (r >= N_TEST) return;
    const unsigned long long* c = cand + (size_t)r * 40;

    unsigned long long top[K_NN];
#pragma unroll
    for (int p = 0; p < K_NN; ++p) top[p] = ~0ull;
#pragma unroll
    for (int i = 0; i < 40; ++i) ins5(c[i], top);

    int labs[K_NN];
#pragma unroll
    for (int p = 0; p < K_NN; ++p) labs[p] = y[(unsigned)(top[p] & 0xffffffffu)];

    int bestLab = 0x7fffffff, bestCnt = 0;
#pragma unroll
    for (int p = 0; p < K_NN; ++p) {
        int cnt = 0;
#pragma unroll
        for (int q = 0; q < K_NN; ++q) cnt += (labs[q] == labs[p]) ? 1 : 0;
        if (cnt > bestCnt || (cnt == bestCnt && labs[p] < bestLab)) {
            bestCnt = cnt; bestLab = labs[p];
        }
    }
    out[r] = bestLab;
}

// ---------------------------------------------------------------------------
// Workspace layout (fp8 path), bytes (NEED unchanged — known-good size):
//   [0,        262144)   x2     : 65536 f32
//   [262144,   278528)   t2     : 4096 f32
//   [278528,  2899968)   cand   : 4096 * 160 u32
//   [3145728, 5242880)   Xte_f8 : 4096*512  e4m3 (2 MB)
//   [7340032, 40894464)  Xtr_f8 : 65536*512 e4m3 (32 MB)
// ---------------------------------------------------------------------------
extern "C" void kernel_launch(void* const* d_in, const int* in_sizes, int n_in,
                              void* d_out, int out_size, void* d_ws, size_t ws_size,
                              hipStream_t stream) {
    const float* Xtr = (const float*)d_in[0];
    const float* Xte = (const float*)d_in[1];
    const int*   y   = (const int*)d_in[2];
    int* out = (int*)d_out;

    char* ws = (char*)d_ws;
    float* x2 = (float*)ws;
    float* t2 = (float*)(ws + 262144);

    const size_t NEED = 74448896;

    if (ws_size >= NEED) {
        unsigned* cand = (unsigned*)(ws + 278528);
        unsigned char* Xte8 = (unsigned char*)(ws + 3145728);
        unsigned char* Xtr8 = (unsigned char*)(ws + 7340032);

        cvtnorm8_k<<<N_TRAIN / 4, 256, 0, stream>>>(Xtr, Xtr8, x2, N_TRAIN);
        cvtnorm8_k<<<N_TEST / 4, 256, 0, stream>>>(Xte, Xte8, t2, N_TEST);

        knn_mfma_k<<<dim3(N_TEST / BTM, NSEG), 512, 0, stream>>>(Xtr8, Xte8, x2, cand);
        rescore_vote_k<<<N_TEST / 4, 256, 0, stream>>>(Xtr, Xte, x2, t2, cand, y, out);
    } else {
        // fp32 fallback (round-1 verified path); cand here is [N_TEST][40] u64
        unsigned long long* cand = (unsigned long long*)(ws + 278528);
        norms_k<<<N_TRAIN / 4, 256, 0, stream>>>(Xtr, x2, N_TRAIN);
        norms_k<<<N_TEST / 4, 256, 0, stream>>>(Xte, t2, N_TEST);
        knn_tile_k<<<dim3(N_TEST / FTM, 8), 256, 0, stream>>>(Xtr, Xte, x2, t2, cand);
        knn_final_k<<<N_TEST / 256, 256, 0, stream>>>(cand, y, out);
    }
}